// Round 13
// baseline (218.248 us; speedup 1.0000x reference)
//
#include <hip/hip_runtime.h>
#include <hip/hip_bf16.h>

#define B_ 8
#define S_ 1024
#define D_ 1024
#define H_ 16
#define DK_ 64
#define M_ (B_*S_)

// 0.125 * log2(e): folds the 1/sqrt(dk) scale AND the exp->exp2 conversion into Q
#define QSCALE 0.1803368801111904f

typedef __attribute__((ext_vector_type(4))) float f32x4;
typedef __attribute__((ext_vector_type(8))) short bf16x8;
typedef __attribute__((ext_vector_type(4))) short s16x4;
typedef __hip_bfloat16 bf16;
typedef unsigned long long ull;

#define GLOAD_LDS16(gp, lp) __builtin_amdgcn_global_load_lds( \
    (const __attribute__((address_space(1))) void*)(gp), \
    (__attribute__((address_space(3))) void*)(lp), 16, 0, 0)

#define SBAR()   asm volatile("s_barrier" ::: "memory")
#define VMCNT(n) asm volatile("s_waitcnt vmcnt(" #n ")" ::: "memory")

__device__ __forceinline__ bf16x8 ld8(const bf16* p){ return *(const bf16x8*)p; }

__device__ __forceinline__ short bf16bits(float f){
  bf16 h = __float2bfloat16(f);
  return __builtin_bit_cast(short, h);
}
__device__ __forceinline__ float tof(short b){
  unsigned u = ((unsigned)(unsigned short)b) << 16;
  return __builtin_bit_cast(float, u);
}

// swizzled LDS fragment read: tile rows of 128B, XOR swizzle byte^=((row&7)<<4)
__device__ __forceinline__ bf16x8 ld8swz(const bf16* base, int row, int colb){
  int sw = colb ^ ((row & 7) << 4);
  return *(const bf16x8*)((const char*)base + row*128 + sw);
}

// DPP 16-lane add reduction — VALU pipe, no LDS traffic
template<int CTRL>
__device__ __forceinline__ float dppadd(float x){
  int m = __builtin_amdgcn_update_dpp(0, __builtin_bit_cast(int,x), CTRL, 0xF, 0xF, true);
  return x + __builtin_bit_cast(float,m);
}
__device__ __forceinline__ float red16add(float x){
  x = dppadd<0xB1>(x);   // quad_perm xor1
  x = dppadd<0x4E>(x);   // quad_perm xor2
  x = dppadd<0x141>(x);  // row_half_mirror
  x = dppadd<0x140>(x);  // row_mirror
  return x;
}

// ---------------- cast f32 -> bf16 ----------------
__global__ __launch_bounds__(256) void cast_f32_bf16(const float* __restrict__ in,
                                                     bf16* __restrict__ out, int n){
  int i = (blockIdx.x*256 + threadIdx.x)*8;
  if (i >= n) return;
  f32x4 a = *(const f32x4*)(in+i);
  f32x4 b = *(const f32x4*)(in+i+4);
  bf16x8 o;
  #pragma unroll
  for (int c=0;c<4;c++){ o[c] = bf16bits(a[c]); o[c+4] = bf16bits(b[c]); }
  *(bf16x8*)(out+i) = o;
}

// all four weight matrices in one launch
__global__ __launch_bounds__(256) void cast_w4(const float* __restrict__ w0, const float* __restrict__ w1,
                                               const float* __restrict__ w2, const float* __restrict__ w3,
                                               bf16* __restrict__ out){
  int sel = blockIdx.x >> 9;
  const float* src = (sel==0)?w0:((sel==1)?w1:((sel==2)?w2:w3));
  int i = (((blockIdx.x & 511)*256) + threadIdx.x)*8;
  f32x4 a = *(const f32x4*)(src+i);
  f32x4 b = *(const f32x4*)(src+i+4);
  bf16x8 o;
  #pragma unroll
  for (int c=0;c<4;c++){ o[c] = bf16bits(a[c]); o[c+4] = bf16bits(b[c]); }
  *(bf16x8*)(out + ((size_t)sel<<20) + i) = o;
}

// ---------------- V column mean (for fully-masked rows) ----------------
__global__ __launch_bounds__(256) void vmean_kernel(const bf16* __restrict__ Vt_g,
                                                    float* __restrict__ vmean){
  int r = blockIdx.x*4 + (threadIdx.x>>6);
  int lane = threadIdx.x & 63;
  const bf16* p = Vt_g + (((size_t)r)<<10) + lane*16;
  bf16x8 a = ld8(p), c = ld8(p+8);
  float s = 0.f;
  #pragma unroll
  for (int e=0;e<8;e++) s += tof(a[e]) + tof(c[e]);
  #pragma unroll
  for (int off=1;off<64;off<<=1) s += __shfl_xor(s, off);
  if (lane==0) vmean[r] = s * (1.f/1024.f);
}

// ---------------- GEMM: C = A * W^T (+bias), 128x128 tile, pipelined staging ----------------
// MODE 0: z=0 -> Q bf16 [B,H,S,dk], pre-scaled by QSCALE; z=1 -> K; z=2 -> V^T [B,H,dk,S]
// MODE 1: O   -> xout f32 = acc + bias + resid
// [benched r10-r12: QKV ~55 us @ ~930 TF]
template<int MODE>
__global__ __launch_bounds__(256) void gemm128(
    const bf16* __restrict__ A,
    const bf16* __restrict__ W0, const bf16* __restrict__ W1, const bf16* __restrict__ W2,
    const float* __restrict__ b0, const float* __restrict__ b1, const float* __restrict__ b2,
    bf16* __restrict__ o0, bf16* __restrict__ o1, bf16* __restrict__ o2,
    const float* __restrict__ resid, float* __restrict__ xout)
{
  const bf16* Wsel = W0; const float* bsel = b0;
  if (MODE==0){
    int z = blockIdx.z;
    Wsel = (z==0)?W0:((z==1)?W1:W2);
    bsel = (z==0)?b0:((z==1)?b1:b2);
  }
  __shared__ bf16 smem[4*128*64];   // 64KB: buf0{A,B}, buf1{A,B}; each buf 32KB
  const int tid = threadIdx.x, wid = tid>>6, lane = tid&63;
  const int lr = lane&15, lg = lane>>4;
  const int m0 = blockIdx.x*128, n0 = blockIdx.y*128;
  const int wr = wid>>1, wc = wid&1;
  f32x4 acc[4][4] = {};

  auto STAGE = [&](int k0, int bsel_){
    #pragma unroll
    for (int c=0;c<4;c++){
      int ldsoff = ((c<<2)|wid)<<10;
      int off = ldsoff + (lane<<4);
      int row = off>>7;
      int colb = (off&127) ^ ((row&7)<<4);
      GLOAD_LDS16(A   + (((size_t)(m0+row))<<10) + k0 + (colb>>1), (char*)smem + bsel_*32768 + ldsoff);
      GLOAD_LDS16(Wsel+ (((size_t)(n0+row))<<10) + k0 + (colb>>1), (char*)smem + bsel_*32768 + 16384 + ldsoff);
    }
  };

  STAGE(0, 0);
  int cur = 0;
  for (int kt=0; kt<16; kt++){
    if (kt < 15){ STAGE((kt+1)<<6, cur^1); VMCNT(8); }  // tile kt's 8 loads (oldest) done
    else        { VMCNT(0); }
    SBAR();
    __builtin_amdgcn_sched_barrier(0);
    const bf16* Asb = smem + cur*16384;
    const bf16* Bsb = Asb + 8192;
    bf16x8 af[4][2], bfv[4][2];
    #pragma unroll
    for (int m=0;m<4;m++){
      int row = wr*64 + m*16 + lr;
      af[m][0] = ld8swz(Asb, row, lg*16);
      af[m][1] = ld8swz(Asb, row, lg*16 + 64);
    }
    #pragma unroll
    for (int n=0;n<4;n++){
      int row = wc*64 + n*16 + lr;
      bfv[n][0] = ld8swz(Bsb, row, lg*16);
      bfv[n][1] = ld8swz(Bsb, row, lg*16 + 64);
    }
    #pragma unroll
    for (int m=0;m<4;m++)
      #pragma unroll
      for (int n=0;n<4;n++){
        acc[m][n] = __builtin_amdgcn_mfma_f32_16x16x32_bf16(af[m][0], bfv[n][0], acc[m][n],0,0,0);
        acc[m][n] = __builtin_amdgcn_mfma_f32_16x16x32_bf16(af[m][1], bfv[n][1], acc[m][n],0,0,0);
      }
    __builtin_amdgcn_sched_barrier(0);
    SBAR();      // all waves done reading buf cur before next iter's loads overwrite it
    cur ^= 1;
  }

  if (MODE==0){
    if (blockIdx.z == 2){
      __syncthreads();
      #pragma unroll
      for (int n=0;n<4;n++){
        int c = wc*64 + n*16 + lr;
        float bias = bsel[n0 + c];
        #pragma unroll
        for (int m=0;m<4;m++){
          int r0 = wr*64 + m*16 + lg*4;
          s16x4 pk;
          #pragma unroll
          for (int j=0;j<4;j++) pk[j] = bf16bits(acc[m][n][j] + bias);
          *(s16x4*)((char*)smem + c*256 + ((r0*2) ^ ((c&7)<<4))) = pk;
        }
      }
      __syncthreads();
      #pragma unroll
      for (int q=0;q<8;q++){
        int idx = tid + q*256;
        int c = idx>>4, r8 = idx&15;
        bf16x8 vv = *(const bf16x8*)((char*)smem + c*256 + ((r8*16) ^ ((c&7)<<4)));
        int col = n0 + c;  int h = col>>6, dd = col&63;
        int row0 = m0 + r8*8;  int bb = row0>>10, s0 = row0&1023;
        *(bf16x8*)(o2 + ((((size_t)bb*H_ + h)*DK_ + dd)<<10) + s0) = vv;
      }
    } else {
      bf16* osel = (blockIdx.z==0) ? o0 : o1;
      const float qs = (blockIdx.z==0) ? QSCALE : 1.0f;   // pre-scale Q for exp2-domain scores
      #pragma unroll
      for (int n=0;n<4;n++){
        int col = n0 + wc*64 + n*16 + lr;
        float bias = bsel[col];
        int h = col>>6, dd = col&63;
        #pragma unroll
        for (int m=0;m<4;m++)
          #pragma unroll
          for (int j=0;j<4;j++){
            int row = m0 + wr*64 + m*16 + lg*4 + j;
            int bb = row>>10, s = row&1023;
            osel[((((size_t)bb*H_ + h)<<10) + s)*DK_ + dd] = __float2bfloat16((acc[m][n][j] + bias)*qs);
          }
      }
    }
  } else {
    #pragma unroll
    for (int n=0;n<4;n++){
      int col = n0 + wc*64 + n*16 + lr;
      float bias = bsel[col];
      #pragma unroll
      for (int m=0;m<4;m++)
        #pragma unroll
        for (int j=0;j<4;j++){
          int row = m0 + wr*64 + m*16 + lg*4 + j;
          size_t idx = (((size_t)row)<<10) + col;
          xout[idx] = acc[m][n][j] + bias + resid[idx];
        }
    }
  }
}

// ---------------- fused causal attention: DIRECT K/V loads, barrier-free, static-max -----------
// Theory (r12 post-mortem): LDS pipe was ~90% busy (kf+vf+Ps ~375 cy/wave-tile); moving K/V
// fragment loads to global (16B/lane, L1/L2-hot; 4 same-bh blocks share an XCD L2) leaves only
// the Ps transpose on the LDS pipe and removes ALL main-loop barriers (waves free-run).
// Keeps: static-max exp2 softmax, antidiagonal wave balance, DPP final reduce, vmean fallback.
__global__ __launch_bounds__(512) void attn_kernel(
    const bf16* __restrict__ Q, const bf16* __restrict__ K, const bf16* __restrict__ Vt_g,
    const int* __restrict__ seqm, const float* __restrict__ vmean, bf16* __restrict__ ctxout)
{
  __shared__ bf16 Ps[8][32*72];   // per-wave P scratch (wave-private -> no barrier needed)
  __shared__ int msk[1024];
  const int tid = threadIdx.x, wid = tid>>6, lane = tid&63;
  const int lr = lane&15, lg = lane>>4;
  const int bh = blockIdx.x, xb = blockIdx.y;
  const int b = bh>>4, h = bh&15;
  const bf16* Qb  = Q    + (size_t)bh * S_ * DK_;
  const bf16* Kb  = K    + (size_t)bh * S_ * DK_;
  const bf16* Vtb = Vt_g + (size_t)bh * DK_ * S_;
  for (int i=tid;i<1024;i+=512) msk[i] = seqm[b*1024+i];

  const int g0 = 8*xb + wid;
  const int rb0 = g0*16;             // low group
  const int rb1 = (63 - g0)*16;      // high group (rb1 > rb0 always)
  bf16x8 qf[2][2];
  {
    const bf16* p0 = Qb + (size_t)(rb0+lr)*DK_ + lg*8;
    const bf16* p1 = Qb + (size_t)(rb1+lr)*DK_ + lg*8;
    qf[0][0] = ld8(p0); qf[0][1] = ld8(p0+32);
    qf[1][0] = ld8(p1); qf[1][1] = ld8(p1+32);
  }
  f32x4 cacc[2][4] = {};
  float lsum[2][4] = {};

  __syncthreads();   // msk ready (only barrier in the kernel)

  // per-lane key-padding bitmask: bit i = msk[i*16 + lr]
  ull mbits = 0;
  #pragma unroll
  for (int i=0;i<64;i++) mbits |= ((ull)(msk[i*16+lr]!=0)) << i;

  const int ntw = ((rb1 + 15) >> 6) + 1;   // wave-local tile count, no lockstep

  for (int t=0; t<ntw; t++){
    const int j0 = t*64;
    const bool act0 = (j0 <= rb0 + 15);

    // K fragments direct from global (16B/lane; 16 full cache lines per nf-pair)
    bf16x8 kf[4][2];
    #pragma unroll
    for (int nf=0;nf<4;nf++){
      const bf16* kp = Kb + (size_t)(j0 + nf*16 + lr)*DK_ + lg*8;
      kf[nf][0] = ld8(kp); kf[nf][1] = ld8(kp+32);
    }

    // per-nf key-padding addend (shared by both frags)
    float madd[4];
    #pragma unroll
    for (int nf=0;nf<4;nf++)
      madd[nf] = ((mbits >> (t*4 + nf)) & 1ull) ? 0.f : -1.0e9f;

    #pragma unroll
    for (int mf=0;mf<2;mf++){
      if (mf==0 && !act0) continue;
      const int rbm = mf ? rb1 : rb0;
      const bool diag = (j0 + 63 > rbm);   // tile touches/crosses the diagonal
      f32x4 sc[4] = {};
      #pragma unroll
      for (int nf=0;nf<4;nf++){
        sc[nf] = __builtin_amdgcn_mfma_f32_16x16x32_bf16(qf[mf][0], kf[nf][0], sc[nf],0,0,0);
        sc[nf] = __builtin_amdgcn_mfma_f32_16x16x32_bf16(qf[mf][1], kf[nf][1], sc[nf],0,0,0);
      }
      // static-max softmax: p = exp2(s + madd); per-lane partial row-sum only
      #pragma unroll
      for (int j=0;j<4;j++){
        int row = rbm + lg*4 + j;
        float ps = 0.f;
        #pragma unroll
        for (int nf=0;nf<4;nf++){
          float s = sc[nf][j] + madd[nf];
          if (diag){
            int col = j0 + nf*16 + lr;
            s = (col <= row) ? s : -1.0e9f;
          }
          float p = exp2f(s);
          sc[nf][j] = p;
          ps += p;
        }
        lsum[mf][j] += ps;
      }
      #pragma unroll
      for (int nf=0;nf<4;nf++)
        #pragma unroll
        for (int j=0;j<4;j++)
          Ps[wid][(mf*16+lg*4+j)*72 + nf*16+lr] = __float2bfloat16(sc[nf][j]);
    }

    // P fragments from per-wave LDS (the 16x16 transpose; in-order within wave)
    bf16x8 pf[2][2];
    #pragma unroll
    for (int mf=0;mf<2;mf++){
      if (mf==0 && !act0) continue;
      const bf16* p = &Ps[wid][(mf*16+lr)*72 + lg*8];
      pf[mf][0] = *(const bf16x8*)p; pf[mf][1] = *(const bf16x8*)(p+32);
    }

    // PV in two df-batches (vf direct from global V^T; keeps VGPR footprint bounded)
    #pragma unroll
    for (int half=0;half<2;half++){
      bf16x8 vf[2][2];
      #pragma unroll
      for (int df=0;df<2;df++){
        const bf16* vp = Vtb + (size_t)((half*2+df)*16+lr)*S_ + j0 + lg*8;
        vf[df][0] = ld8(vp); vf[df][1] = ld8(vp+32);
      }
      __builtin_amdgcn_s_setprio(1);
      #pragma unroll
      for (int df=0;df<2;df++){
        #pragma unroll
        for (int kk=0;kk<2;kk++){
          if (act0)
            cacc[0][half*2+df] = __builtin_amdgcn_mfma_f32_16x16x32_bf16(pf[0][kk], vf[df][kk], cacc[0][half*2+df],0,0,0);
          cacc[1][half*2+df] = __builtin_amdgcn_mfma_f32_16x16x32_bf16(pf[1][kk], vf[df][kk], cacc[1][half*2+df],0,0,0);
        }
      }
      __builtin_amdgcn_s_setprio(0);
    }
  }

  #pragma unroll
  for (int mf=0;mf<2;mf++){
    const int rbm = mf ? rb1 : rb0;
    float lt[4];
    #pragma unroll
    for (int j=0;j<4;j++) lt[j] = red16add(lsum[mf][j]);   // row-sum reduce, once
    #pragma unroll
    for (int df=0;df<4;df++)
      #pragma unroll
      for (int j=0;j<4;j++){
        int srow = rbm + lg*4 + j;
        int dd = df*16 + lr;
        float v = cacc[mf][df][j] / lt[j];
        if (lt[j] <= 1.0e-30f) v = vmean[bh*64 + dd];  // fully-masked row (lsum == 0)
        ctxout[((size_t)b*S_ + srow)*D_ + h*DK_ + dd] = __float2bfloat16(v);
      }
  }
}

// ---------------- LayerNorm ----------------
__global__ __launch_bounds__(256) void ln_kernel(const float* __restrict__ X2,
    const float* __restrict__ gamma, const float* __restrict__ beta, float* __restrict__ out)
{
  const int row = blockIdx.x, tid = threadIdx.x;
  const int lane = tid&63, wid = tid>>6;
  const f32x4* xr = (const f32x4*)(X2 + (((size_t)row)<<10));
  f32x4 v = xr[tid];
  float s  = v[0]+v[1]+v[2]+v[3];
  float s2 = v[0]*v[0]+v[1]*v[1]+v[2]*v[2]+v[3]*v[3];
  #pragma unroll
  for (int off=1;off<64;off<<=1){ s += __shfl_xor(s,off); s2 += __shfl_xor(s2,off); }
  __shared__ float red[8];
  if (lane==0){ red[wid]=s; red[wid+4]=s2; }
  __syncthreads();
  s  = red[0]+red[1]+red[2]+red[3];
  s2 = red[4]+red[5]+red[6]+red[7];
  float mu  = s*(1.f/1024.f);
  float var = s2*(1.f/1024.f) - mu*mu;
  float inv = rsqrtf(var + 1e-5f);
  f32x4 gv = ((const f32x4*)gamma)[tid], bv = ((const f32x4*)beta)[tid];
  f32x4 o;
  #pragma unroll
  for (int c=0;c<4;c++) o[c] = (v[c]-mu)*inv*gv[c] + bv[c];
  ((f32x4*)(out + (((size_t)row)<<10)))[tid] = o;
}

extern "C" void kernel_launch(void* const* d_in, const int* in_sizes, int n_in,
                              void* d_out, int out_size, void* d_ws, size_t ws_size,
                              hipStream_t stream) {
  const float* X   = (const float*)d_in[0];
  const int*   sm  = (const int*)d_in[1];
  const float* Wq  = (const float*)d_in[2];  const float* bq = (const float*)d_in[3];
  const float* Wk  = (const float*)d_in[4];  const float* bk = (const float*)d_in[5];
  const float* Wv  = (const float*)d_in[6];  const float* bv = (const float*)d_in[7];
  const float* Wo  = (const float*)d_in[8];  const float* bo = (const float*)d_in[9];
  const float* ga  = (const float*)d_in[10]; const float* be = (const float*)d_in[11];
  float* out = (float*)d_out;
  char* ws = (char*)d_ws;

  bf16* Xbf = (bf16*)(ws);                       // 16 MB
  bf16* Wqb = (bf16*)(ws + (16u<<20));           // 2 MB each, contiguous
  bf16* Wkb = (bf16*)(ws + (18u<<20));
  bf16* Wvb = (bf16*)(ws + (20u<<20));
  bf16* Wob = (bf16*)(ws + (22u<<20));
  bf16* Qh  = (bf16*)(ws + (24u<<20));           // 16 MB  [B,H,S,dk] (pre-scaled)
  bf16* Kh  = (bf16*)(ws + (40u<<20));           // 16 MB  [B,H,S,dk]
  bf16* Vth = (bf16*)(ws + (56u<<20));           // 16 MB  V^T [B,H,dk,S]
  bf16* Ctx = (bf16*)(ws + (72u<<20));           // 16 MB  [B,S,D]
  float* X2 = (float*)(ws + (24u<<20));          // 32 MB, aliases Qh/Kh (dead after attn)
  float* vmean = (float*)(ws + (16u<<20));       // 32 KB, aliases Wqb (dead after gemm<0>)

  cast_f32_bf16<<<4096,256,0,stream>>>(X,  Xbf, M_*D_);
  cast_w4<<<2048,256,0,stream>>>(Wq, Wk, Wv, Wo, Wqb);

  dim3 g1(M_/128, D_/128, 3);
  gemm128<0><<<g1,256,0,stream>>>(Xbf, Wqb,Wkb,Wvb, bq,bk,bv, Qh,Kh,Vth, nullptr, nullptr);

  vmean_kernel<<<B_*H_*DK_/4,256,0,stream>>>(Vth, vmean);

  dim3 g2(B_*H_, 4);
  attn_kernel<<<g2,512,0,stream>>>(Qh, Kh, Vth, sm, vmean, Ctx);

  dim3 g3(M_/128, D_/128, 1);
  gemm128<1><<<g3,256,0,stream>>>(Ctx, Wob,nullptr,nullptr, bo,nullptr,nullptr,
                                  nullptr,nullptr,nullptr, X, X2);

  ln_kernel<<<M_,256,0,stream>>>(X2, ga, be, out);
}

// Round 14
// 198.318 us; speedup vs baseline: 1.1005x; 1.1005x over previous
//
#include <hip/hip_runtime.h>
#include <hip/hip_bf16.h>

#define B_ 8
#define S_ 1024
#define D_ 1024
#define H_ 16
#define DK_ 64
#define M_ (B_*S_)

// 0.125 * log2(e): folds the 1/sqrt(dk) scale AND the exp->exp2 conversion into Q
#define QSCALE 0.1803368801111904f

typedef __attribute__((ext_vector_type(4))) float f32x4;
typedef __attribute__((ext_vector_type(8))) short bf16x8;
typedef __attribute__((ext_vector_type(4))) short s16x4;
typedef __hip_bfloat16 bf16;
typedef unsigned long long ull;

#define GLOAD_LDS16(gp, lp) __builtin_amdgcn_global_load_lds( \
    (const __attribute__((address_space(1))) void*)(gp), \
    (__attribute__((address_space(3))) void*)(lp), 16, 0, 0)

#define SBAR()   asm volatile("s_barrier" ::: "memory")
#define VMCNT(n) asm volatile("s_waitcnt vmcnt(" #n ")" ::: "memory")

__device__ __forceinline__ bf16x8 ld8(const bf16* p){ return *(const bf16x8*)p; }

__device__ __forceinline__ short bf16bits(float f){
  bf16 h = __float2bfloat16(f);
  return __builtin_bit_cast(short, h);
}
__device__ __forceinline__ float tof(short b){
  unsigned u = ((unsigned)(unsigned short)b) << 16;
  return __builtin_bit_cast(float, u);
}

// swizzled LDS fragment read: tile rows of 128B, XOR swizzle byte^=((row&7)<<4)
__device__ __forceinline__ bf16x8 ld8swz(const bf16* base, int row, int colb){
  int sw = colb ^ ((row & 7) << 4);
  return *(const bf16x8*)((const char*)base + row*128 + sw);
}

// DPP 16-lane add reduction — VALU pipe, no LDS traffic
template<int CTRL>
__device__ __forceinline__ float dppadd(float x){
  int m = __builtin_amdgcn_update_dpp(0, __builtin_bit_cast(int,x), CTRL, 0xF, 0xF, true);
  return x + __builtin_bit_cast(float,m);
}
__device__ __forceinline__ float red16add(float x){
  x = dppadd<0xB1>(x);   // quad_perm xor1
  x = dppadd<0x4E>(x);   // quad_perm xor2
  x = dppadd<0x141>(x);  // row_half_mirror
  x = dppadd<0x140>(x);  // row_mirror
  return x;
}

// ---------------- cast f32 -> bf16 ----------------
__global__ __launch_bounds__(256) void cast_f32_bf16(const float* __restrict__ in,
                                                     bf16* __restrict__ out, int n){
  int i = (blockIdx.x*256 + threadIdx.x)*8;
  if (i >= n) return;
  f32x4 a = *(const f32x4*)(in+i);
  f32x4 b = *(const f32x4*)(in+i+4);
  bf16x8 o;
  #pragma unroll
  for (int c=0;c<4;c++){ o[c] = bf16bits(a[c]); o[c+4] = bf16bits(b[c]); }
  *(bf16x8*)(out+i) = o;
}

// all four weight matrices in one launch
__global__ __launch_bounds__(256) void cast_w4(const float* __restrict__ w0, const float* __restrict__ w1,
                                               const float* __restrict__ w2, const float* __restrict__ w3,
                                               bf16* __restrict__ out){
  int sel = blockIdx.x >> 9;
  const float* src = (sel==0)?w0:((sel==1)?w1:((sel==2)?w2:w3));
  int i = (((blockIdx.x & 511)*256) + threadIdx.x)*8;
  f32x4 a = *(const f32x4*)(src+i);
  f32x4 b = *(const f32x4*)(src+i+4);
  bf16x8 o;
  #pragma unroll
  for (int c=0;c<4;c++){ o[c] = bf16bits(a[c]); o[c+4] = bf16bits(b[c]); }
  *(bf16x8*)(out + ((size_t)sel<<20) + i) = o;
}

// ---------------- V column mean (for fully-masked rows) ----------------
__global__ __launch_bounds__(256) void vmean_kernel(const bf16* __restrict__ Vt_g,
                                                    float* __restrict__ vmean){
  int r = blockIdx.x*4 + (threadIdx.x>>6);
  int lane = threadIdx.x & 63;
  const bf16* p = Vt_g + (((size_t)r)<<10) + lane*16;
  bf16x8 a = ld8(p), c = ld8(p+8);
  float s = 0.f;
  #pragma unroll
  for (int e=0;e<8;e++) s += tof(a[e]) + tof(c[e]);
  #pragma unroll
  for (int off=1;off<64;off<<=1) s += __shfl_xor(s, off);
  if (lane==0) vmean[r] = s * (1.f/1024.f);
}

// ---------------- GEMM: C = A * W^T (+bias), 128x128 tile, pipelined staging ----------------
// MODE 0: z=0 -> Q bf16 [B,H,S,dk], pre-scaled by QSCALE; z=1 -> K; z=2 -> V^T [B,H,dk,S]
// MODE 1: O   -> xout f32 = acc + bias + resid
// [benched r10-r12: QKV ~55 us @ ~930 TF — unchanged]
template<int MODE>
__global__ __launch_bounds__(256) void gemm128(
    const bf16* __restrict__ A,
    const bf16* __restrict__ W0, const bf16* __restrict__ W1, const bf16* __restrict__ W2,
    const float* __restrict__ b0, const float* __restrict__ b1, const float* __restrict__ b2,
    bf16* __restrict__ o0, bf16* __restrict__ o1, bf16* __restrict__ o2,
    const float* __restrict__ resid, float* __restrict__ xout)
{
  const bf16* Wsel = W0; const float* bsel = b0;
  if (MODE==0){
    int z = blockIdx.z;
    Wsel = (z==0)?W0:((z==1)?W1:W2);
    bsel = (z==0)?b0:((z==1)?b1:b2);
  }
  __shared__ bf16 smem[4*128*64];   // 64KB: buf0{A,B}, buf1{A,B}; each buf 32KB
  const int tid = threadIdx.x, wid = tid>>6, lane = tid&63;
  const int lr = lane&15, lg = lane>>4;
  const int m0 = blockIdx.x*128, n0 = blockIdx.y*128;
  const int wr = wid>>1, wc = wid&1;
  f32x4 acc[4][4] = {};

  auto STAGE = [&](int k0, int bsel_){
    #pragma unroll
    for (int c=0;c<4;c++){
      int ldsoff = ((c<<2)|wid)<<10;
      int off = ldsoff + (lane<<4);
      int row = off>>7;
      int colb = (off&127) ^ ((row&7)<<4);
      GLOAD_LDS16(A   + (((size_t)(m0+row))<<10) + k0 + (colb>>1), (char*)smem + bsel_*32768 + ldsoff);
      GLOAD_LDS16(Wsel+ (((size_t)(n0+row))<<10) + k0 + (colb>>1), (char*)smem + bsel_*32768 + 16384 + ldsoff);
    }
  };

  STAGE(0, 0);
  int cur = 0;
  for (int kt=0; kt<16; kt++){
    if (kt < 15){ STAGE((kt+1)<<6, cur^1); VMCNT(8); }  // tile kt's 8 loads (oldest) done
    else        { VMCNT(0); }
    SBAR();
    __builtin_amdgcn_sched_barrier(0);
    const bf16* Asb = smem + cur*16384;
    const bf16* Bsb = Asb + 8192;
    bf16x8 af[4][2], bfv[4][2];
    #pragma unroll
    for (int m=0;m<4;m++){
      int row = wr*64 + m*16 + lr;
      af[m][0] = ld8swz(Asb, row, lg*16);
      af[m][1] = ld8swz(Asb, row, lg*16 + 64);
    }
    #pragma unroll
    for (int n=0;n<4;n++){
      int row = wc*64 + n*16 + lr;
      bfv[n][0] = ld8swz(Bsb, row, lg*16);
      bfv[n][1] = ld8swz(Bsb, row, lg*16 + 64);
    }
    #pragma unroll
    for (int m=0;m<4;m++)
      #pragma unroll
      for (int n=0;n<4;n++){
        acc[m][n] = __builtin_amdgcn_mfma_f32_16x16x32_bf16(af[m][0], bfv[n][0], acc[m][n],0,0,0);
        acc[m][n] = __builtin_amdgcn_mfma_f32_16x16x32_bf16(af[m][1], bfv[n][1], acc[m][n],0,0,0);
      }
    __builtin_amdgcn_sched_barrier(0);
    SBAR();      // all waves done reading buf cur before next iter's loads overwrite it
    cur ^= 1;
  }

  if (MODE==0){
    if (blockIdx.z == 2){
      __syncthreads();
      #pragma unroll
      for (int n=0;n<4;n++){
        int c = wc*64 + n*16 + lr;
        float bias = bsel[n0 + c];
        #pragma unroll
        for (int m=0;m<4;m++){
          int r0 = wr*64 + m*16 + lg*4;
          s16x4 pk;
          #pragma unroll
          for (int j=0;j<4;j++) pk[j] = bf16bits(acc[m][n][j] + bias);
          *(s16x4*)((char*)smem + c*256 + ((r0*2) ^ ((c&7)<<4))) = pk;
        }
      }
      __syncthreads();
      #pragma unroll
      for (int q=0;q<8;q++){
        int idx = tid + q*256;
        int c = idx>>4, r8 = idx&15;
        bf16x8 vv = *(const bf16x8*)((char*)smem + c*256 + ((r8*16) ^ ((c&7)<<4)));
        int col = n0 + c;  int h = col>>6, dd = col&63;
        int row0 = m0 + r8*8;  int bb = row0>>10, s0 = row0&1023;
        *(bf16x8*)(o2 + ((((size_t)bb*H_ + h)*DK_ + dd)<<10) + s0) = vv;
      }
    } else {
      bf16* osel = (blockIdx.z==0) ? o0 : o1;
      const float qs = (blockIdx.z==0) ? QSCALE : 1.0f;   // pre-scale Q for exp2-domain scores
      #pragma unroll
      for (int n=0;n<4;n++){
        int col = n0 + wc*64 + n*16 + lr;
        float bias = bsel[col];
        int h = col>>6, dd = col&63;
        #pragma unroll
        for (int m=0;m<4;m++)
          #pragma unroll
          for (int j=0;j<4;j++){
            int row = m0 + wr*64 + m*16 + lg*4 + j;
            int bb = row>>10, s = row&1023;
            osel[((((size_t)bb*H_ + h)<<10) + s)*DK_ + dd] = __float2bfloat16((acc[m][n][j] + bias)*qs);
          }
      }
    }
  } else {
    #pragma unroll
    for (int n=0;n<4;n++){
      int col = n0 + wc*64 + n*16 + lr;
      float bias = bsel[col];
      #pragma unroll
      for (int m=0;m<4;m++)
        #pragma unroll
        for (int j=0;j<4;j++){
          int row = m0 + wr*64 + m*16 + lg*4 + j;
          size_t idx = (((size_t)row)<<10) + col;
          xout[idx] = acc[m][n][j] + bias + resid[idx];
        }
    }
  }
}

// ---------------- fused causal attention: 1-frag/wave, high-occupancy, reg-staged ----------------
// Theory (r13 post-mortem): staged attn is issue-bound with only 16 waves/CU (512-block grid,
// 73.7KB LDS). Restructure: wave owns ONE 16-row group g = 8*xb + w; grid (xb=8 fast, bh=128)
// = 1024 blocks; LDS diet (single-buffer K/V 16KB + swizzled Ps 16KB + byte mask 1KB = ~34KB)
// + launch_bounds(512,3) -> 24 waves/CU. Single-buffer latency hidden by T14 reg-staged split:
// issue next-tile global loads -> compute(t) -> sync -> ds_write from regs -> sync.
__global__ __launch_bounds__(512, 3) void attn_kernel(
    const bf16* __restrict__ Q, const bf16* __restrict__ K, const bf16* __restrict__ Vt_g,
    const int* __restrict__ seqm, const float* __restrict__ vmean, bf16* __restrict__ ctxout)
{
  __shared__ bf16 Ks[64*64];      // K tile   [kv][d], swizzled, single-buffered (8KB)
  __shared__ bf16 Vs[64*64];      // V^T tile [d][kv], swizzled, single-buffered (8KB)
  __shared__ bf16 Ps[8][16*64];   // per-wave P scratch, 16 rows, swizzled stride-64 (16KB)
  __shared__ unsigned char mskb[1024];
  const int tid = threadIdx.x, wid = tid>>6, lane = tid&63;
  const int lr = lane&15, lg = lane>>4;
  const int xb = blockIdx.x, bh = blockIdx.y;   // xb fastest: long blocks dispatch early
  const int b = bh>>4, h = bh&15;
  const bf16* Qb  = Q    + (size_t)bh * S_ * DK_;
  const bf16* Kb  = K    + (size_t)bh * S_ * DK_;
  const bf16* Vtb = Vt_g + (size_t)bh * DK_ * S_;
  for (int i=tid;i<1024;i+=512) mskb[i] = (unsigned char)(seqm[b*1024+i]!=0);

  const int g0 = 8*xb + wid;         // this wave's 16-row group (0..63)
  const int rb = g0*16;
  bf16x8 qf[2];
  {
    const bf16* p0 = Qb + (size_t)(rb+lr)*DK_ + lg*8;
    qf[0] = ld8(p0); qf[1] = ld8(p0+32);
  }
  f32x4 cacc[4] = {};
  float lsum[4] = {};

  // reg-staged K/V: each thread owns 16B of K and 16B of V per tile
  const int srow = tid>>3;           // 0..63
  const int scolb = (tid&7)*16;      // byte col within 128B row
  const int ssw = scolb ^ ((srow&7)<<4);
  bf16x8 kr, vr;
  auto STAGE_LOAD = [&](int t){
    const int j0 = t*64;
    kr = ld8(Kb  + (size_t)(j0+srow)*DK_ + (scolb>>1));
    vr = ld8(Vtb + (((size_t)srow)<<10) + j0 + (scolb>>1));
  };
  auto STAGE_WRITE = [&](){
    *(bf16x8*)((char*)Ks + srow*128 + ssw) = kr;
    *(bf16x8*)((char*)Vs + srow*128 + ssw) = vr;
  };

  const int bnt = 2*xb + 2;          // block tile count (max over its waves)

  STAGE_LOAD(0);
  STAGE_WRITE();                     // compiler inserts the vmcnt wait on kr/vr use
  if (bnt > 1) STAGE_LOAD(1);        // in flight during round 0 compute
  __syncthreads();                   // tile0 + mskb visible

  // per-lane key-padding bitmask: bit i = mskb[i*16 + lr]
  ull mbits = 0;
  #pragma unroll
  for (int i=0;i<64;i++) mbits |= ((ull)mskb[i*16+lr]) << i;

  for (int t=0; t<bnt; t++){
    const int j0 = t*64;
    if (j0 <= rb + 15){              // wave active for this tile
      bf16x8 kf[4][2];
      #pragma unroll
      for (int nf=0;nf<4;nf++){
        kf[nf][0] = ld8swz(Ks, nf*16+lr, lg*16);
        kf[nf][1] = ld8swz(Ks, nf*16+lr, lg*16 + 64);
      }
      float madd[4];
      #pragma unroll
      for (int nf=0;nf<4;nf++)
        madd[nf] = ((mbits >> (t*4 + nf)) & 1ull) ? 0.f : -1.0e9f;

      const bool diag = (j0 + 63 > rb);
      f32x4 sc[4] = {};
      #pragma unroll
      for (int nf=0;nf<4;nf++){
        sc[nf] = __builtin_amdgcn_mfma_f32_16x16x32_bf16(qf[0], kf[nf][0], sc[nf],0,0,0);
        sc[nf] = __builtin_amdgcn_mfma_f32_16x16x32_bf16(qf[1], kf[nf][1], sc[nf],0,0,0);
      }
      // static-max softmax: p = exp2(s + madd); per-lane partial row-sum only
      #pragma unroll
      for (int j=0;j<4;j++){
        int row = rb + lg*4 + j;
        float ps = 0.f;
        #pragma unroll
        for (int nf=0;nf<4;nf++){
          float s = sc[nf][j] + madd[nf];
          if (diag){
            int col = j0 + nf*16 + lr;
            s = (col <= row) ? s : -1.0e9f;
          }
          float p = exp2f(s);
          sc[nf][j] = p;
          ps += p;
        }
        lsum[j] += ps;
      }
      // P transpose through wave-private swizzled LDS (write scalar, read b128)
      char* pbase = (char*)&Ps[wid][0];
      #pragma unroll
      for (int nf=0;nf<4;nf++)
        #pragma unroll
        for (int j=0;j<4;j++){
          int prow = lg*4 + j;
          *(short*)(pbase + prow*128 + (((nf*16+lr)*2) ^ ((prow&7)<<4))) = bf16bits(sc[nf][j]);
        }
      bf16x8 pf0 = ld8swz(&Ps[wid][0], lr, lg*16);
      bf16x8 pf1 = ld8swz(&Ps[wid][0], lr, lg*16 + 64);
      // PV
      #pragma unroll
      for (int df=0;df<4;df++){
        bf16x8 vf0 = ld8swz(Vs, df*16+lr, lg*16);
        bf16x8 vf1 = ld8swz(Vs, df*16+lr, lg*16 + 64);
        cacc[df] = __builtin_amdgcn_mfma_f32_16x16x32_bf16(pf0, vf0, cacc[df],0,0,0);
        cacc[df] = __builtin_amdgcn_mfma_f32_16x16x32_bf16(pf1, vf1, cacc[df],0,0,0);
      }
    }
    __syncthreads();                 // all waves done reading Ks/Vs
    if (t+1 < bnt){
      STAGE_WRITE();                 // tile t+1 regs -> LDS (vmcnt wait auto-inserted)
      if (t+2 < bnt) STAGE_LOAD(t+2);// next loads fly under compute(t+1)
      __syncthreads();               // writes visible
    }
  }

  float lt[4];
  #pragma unroll
  for (int j=0;j<4;j++) lt[j] = red16add(lsum[j]);   // row-sum reduce, once
  #pragma unroll
  for (int df=0;df<4;df++)
    #pragma unroll
    for (int j=0;j<4;j++){
      int srow2 = rb + lg*4 + j;
      int dd = df*16 + lr;
      float v = cacc[df][j] / lt[j];
      if (lt[j] <= 1.0e-30f) v = vmean[bh*64 + dd];  // fully-masked row (lsum == 0)
      ctxout[((size_t)b*S_ + srow2)*D_ + h*DK_ + dd] = __float2bfloat16(v);
    }
}

// ---------------- LayerNorm ----------------
__global__ __launch_bounds__(256) void ln_kernel(const float* __restrict__ X2,
    const float* __restrict__ gamma, const float* __restrict__ beta, float* __restrict__ out)
{
  const int row = blockIdx.x, tid = threadIdx.x;
  const int lane = tid&63, wid = tid>>6;
  const f32x4* xr = (const f32x4*)(X2 + (((size_t)row)<<10));
  f32x4 v = xr[tid];
  float s  = v[0]+v[1]+v[2]+v[3];
  float s2 = v[0]*v[0]+v[1]*v[1]+v[2]*v[2]+v[3]*v[3];
  #pragma unroll
  for (int off=1;off<64;off<<=1){ s += __shfl_xor(s,off); s2 += __shfl_xor(s2,off); }
  __shared__ float red[8];
  if (lane==0){ red[wid]=s; red[wid+4]=s2; }
  __syncthreads();
  s  = red[0]+red[1]+red[2]+red[3];
  s2 = red[4]+red[5]+red[6]+red[7];
  float mu  = s*(1.f/1024.f);
  float var = s2*(1.f/1024.f) - mu*mu;
  float inv = rsqrtf(var + 1e-5f);
  f32x4 gv = ((const f32x4*)gamma)[tid], bv = ((const f32x4*)beta)[tid];
  f32x4 o;
  #pragma unroll
  for (int c=0;c<4;c++) o[c] = (v[c]-mu)*inv*gv[c] + bv[c];
  ((f32x4*)(out + (((size_t)row)<<10)))[tid] = o;
}

extern "C" void kernel_launch(void* const* d_in, const int* in_sizes, int n_in,
                              void* d_out, int out_size, void* d_ws, size_t ws_size,
                              hipStream_t stream) {
  const float* X   = (const float*)d_in[0];
  const int*   sm  = (const int*)d_in[1];
  const float* Wq  = (const float*)d_in[2];  const float* bq = (const float*)d_in[3];
  const float* Wk  = (const float*)d_in[4];  const float* bk = (const float*)d_in[5];
  const float* Wv  = (const float*)d_in[6];  const float* bv = (const float*)d_in[7];
  const float* Wo  = (const float*)d_in[8];  const float* bo = (const float*)d_in[9];
  const float* ga  = (const float*)d_in[10]; const float* be = (const float*)d_in[11];
  float* out = (float*)d_out;
  char* ws = (char*)d_ws;

  bf16* Xbf = (bf16*)(ws);                       // 16 MB
  bf16* Wqb = (bf16*)(ws + (16u<<20));           // 2 MB each, contiguous
  bf16* Wkb = (bf16*)(ws + (18u<<20));
  bf16* Wvb = (bf16*)(ws + (20u<<20));
  bf16* Wob = (bf16*)(ws + (22u<<20));
  bf16* Qh  = (bf16*)(ws + (24u<<20));           // 16 MB  [B,H,S,dk] (pre-scaled)
  bf16* Kh  = (bf16*)(ws + (40u<<20));           // 16 MB  [B,H,S,dk]
  bf16* Vth = (bf16*)(ws + (56u<<20));           // 16 MB  V^T [B,H,dk,S]
  bf16* Ctx = (bf16*)(ws + (72u<<20));           // 16 MB  [B,S,D]
  float* X2 = (float*)(ws + (24u<<20));          // 32 MB, aliases Qh/Kh (dead after attn)
  float* vmean = (float*)(ws + (16u<<20));       // 32 KB, aliases Wqb (dead after gemm<0>)

  cast_f32_bf16<<<4096,256,0,stream>>>(X,  Xbf, M_*D_);
  cast_w4<<<2048,256,0,stream>>>(Wq, Wk, Wv, Wo, Wqb);

  dim3 g1(M_/128, D_/128, 3);
  gemm128<0><<<g1,256,0,stream>>>(Xbf, Wqb,Wkb,Wvb, bq,bk,bv, Qh,Kh,Vth, nullptr, nullptr);

  vmean_kernel<<<B_*H_*DK_/4,256,0,stream>>>(Vth, vmean);

  dim3 g2(8, B_*H_);   // xb fastest -> long (high-xb) blocks dispatch early
  attn_kernel<<<g2,512,0,stream>>>(Qh, Kh, Vth, sm, vmean, Ctx);

  dim3 g3(M_/128, D_/128, 1);
  gemm128<1><<<g3,256,0,stream>>>(Ctx, Wob,nullptr,nullptr, bo,nullptr,nullptr,
                                  nullptr,nullptr,nullptr, X, X2);

  ln_kernel<<<M_,256,0,stream>>>(X2, ga, be, out);
}

// Round 15
// 181.896 us; speedup vs baseline: 1.1998x; 1.0903x over previous
//
#include <hip/hip_runtime.h>
#include <hip/hip_bf16.h>

#define B_ 8
#define S_ 1024
#define D_ 1024
#define H_ 16
#define DK_ 64
#define M_ (B_*S_)

// 0.125 * log2(e): folds the 1/sqrt(dk) scale AND the exp->exp2 conversion into Q
#define QSCALE 0.1803368801111904f

typedef __attribute__((ext_vector_type(4))) float f32x4;
typedef __attribute__((ext_vector_type(8))) short bf16x8;
typedef __attribute__((ext_vector_type(4))) short s16x4;
typedef __hip_bfloat16 bf16;
typedef unsigned long long ull;

#define GLOAD_LDS16(gp, lp) __builtin_amdgcn_global_load_lds( \
    (const __attribute__((address_space(1))) void*)(gp), \
    (__attribute__((address_space(3))) void*)(lp), 16, 0, 0)

#define SBAR()   asm volatile("s_barrier" ::: "memory")
#define VMCNT(n) asm volatile("s_waitcnt vmcnt(" #n ")" ::: "memory")

__device__ __forceinline__ bf16x8 ld8(const bf16* p){ return *(const bf16x8*)p; }

__device__ __forceinline__ short bf16bits(float f){
  bf16 h = __float2bfloat16(f);
  return __builtin_bit_cast(short, h);
}
__device__ __forceinline__ float tof(short b){
  unsigned u = ((unsigned)(unsigned short)b) << 16;
  return __builtin_bit_cast(float, u);
}

// swizzled LDS fragment read: tile rows of 128B, XOR swizzle byte^=((row&7)<<4)
__device__ __forceinline__ bf16x8 ld8swz(const bf16* base, int row, int colb){
  int sw = colb ^ ((row & 7) << 4);
  return *(const bf16x8*)((const char*)base + row*128 + sw);
}

// DPP 16-lane add reduction — VALU pipe, no LDS traffic
template<int CTRL>
__device__ __forceinline__ float dppadd(float x){
  int m = __builtin_amdgcn_update_dpp(0, __builtin_bit_cast(int,x), CTRL, 0xF, 0xF, true);
  return x + __builtin_bit_cast(float,m);
}
__device__ __forceinline__ float red16add(float x){
  x = dppadd<0xB1>(x);   // quad_perm xor1
  x = dppadd<0x4E>(x);   // quad_perm xor2
  x = dppadd<0x141>(x);  // row_half_mirror
  x = dppadd<0x140>(x);  // row_mirror
  return x;
}

// ---------------- cast f32 -> bf16 ----------------
__global__ __launch_bounds__(256) void cast_f32_bf16(const float* __restrict__ in,
                                                     bf16* __restrict__ out, int n){
  int i = (blockIdx.x*256 + threadIdx.x)*8;
  if (i >= n) return;
  f32x4 a = *(const f32x4*)(in+i);
  f32x4 b = *(const f32x4*)(in+i+4);
  bf16x8 o;
  #pragma unroll
  for (int c=0;c<4;c++){ o[c] = bf16bits(a[c]); o[c+4] = bf16bits(b[c]); }
  *(bf16x8*)(out+i) = o;
}

// all four weight matrices in one launch
__global__ __launch_bounds__(256) void cast_w4(const float* __restrict__ w0, const float* __restrict__ w1,
                                               const float* __restrict__ w2, const float* __restrict__ w3,
                                               bf16* __restrict__ out){
  int sel = blockIdx.x >> 9;
  const float* src = (sel==0)?w0:((sel==1)?w1:((sel==2)?w2:w3));
  int i = (((blockIdx.x & 511)*256) + threadIdx.x)*8;
  f32x4 a = *(const f32x4*)(src+i);
  f32x4 b = *(const f32x4*)(src+i+4);
  bf16x8 o;
  #pragma unroll
  for (int c=0;c<4;c++){ o[c] = bf16bits(a[c]); o[c+4] = bf16bits(b[c]); }
  *(bf16x8*)(out + ((size_t)sel<<20) + i) = o;
}

// ---------------- V column mean (for fully-masked rows) ----------------
__global__ __launch_bounds__(256) void vmean_kernel(const bf16* __restrict__ Vt_g,
                                                    float* __restrict__ vmean){
  int r = blockIdx.x*4 + (threadIdx.x>>6);
  int lane = threadIdx.x & 63;
  const bf16* p = Vt_g + (((size_t)r)<<10) + lane*16;
  bf16x8 a = ld8(p), c = ld8(p+8);
  float s = 0.f;
  #pragma unroll
  for (int e=0;e<8;e++) s += tof(a[e]) + tof(c[e]);
  #pragma unroll
  for (int off=1;off<64;off<<=1) s += __shfl_xor(s, off);
  if (lane==0) vmean[r] = s * (1.f/1024.f);
}

// ---------------- GEMM: C = A * W^T (+bias), 128x128 tile, pipelined staging ----------------
// MODE 0: z=0 -> Q bf16 [B,H,S,dk], pre-scaled by QSCALE; z=1 -> K; z=2 -> V^T [B,H,dk,S]
// MODE 1: O   -> xout f32 = acc + bias + resid
// [benched r10-r12: QKV ~55 us @ ~930 TF — unchanged]
template<int MODE>
__global__ __launch_bounds__(256) void gemm128(
    const bf16* __restrict__ A,
    const bf16* __restrict__ W0, const bf16* __restrict__ W1, const bf16* __restrict__ W2,
    const float* __restrict__ b0, const float* __restrict__ b1, const float* __restrict__ b2,
    bf16* __restrict__ o0, bf16* __restrict__ o1, bf16* __restrict__ o2,
    const float* __restrict__ resid, float* __restrict__ xout)
{
  const bf16* Wsel = W0; const float* bsel = b0;
  if (MODE==0){
    int z = blockIdx.z;
    Wsel = (z==0)?W0:((z==1)?W1:W2);
    bsel = (z==0)?b0:((z==1)?b1:b2);
  }
  __shared__ bf16 smem[4*128*64];   // 64KB: buf0{A,B}, buf1{A,B}; each buf 32KB
  const int tid = threadIdx.x, wid = tid>>6, lane = tid&63;
  const int lr = lane&15, lg = lane>>4;
  const int m0 = blockIdx.x*128, n0 = blockIdx.y*128;
  const int wr = wid>>1, wc = wid&1;
  f32x4 acc[4][4] = {};

  auto STAGE = [&](int k0, int bsel_){
    #pragma unroll
    for (int c=0;c<4;c++){
      int ldsoff = ((c<<2)|wid)<<10;
      int off = ldsoff + (lane<<4);
      int row = off>>7;
      int colb = (off&127) ^ ((row&7)<<4);
      GLOAD_LDS16(A   + (((size_t)(m0+row))<<10) + k0 + (colb>>1), (char*)smem + bsel_*32768 + ldsoff);
      GLOAD_LDS16(Wsel+ (((size_t)(n0+row))<<10) + k0 + (colb>>1), (char*)smem + bsel_*32768 + 16384 + ldsoff);
    }
  };

  STAGE(0, 0);
  int cur = 0;
  for (int kt=0; kt<16; kt++){
    if (kt < 15){ STAGE((kt+1)<<6, cur^1); VMCNT(8); }  // tile kt's 8 loads (oldest) done
    else        { VMCNT(0); }
    SBAR();
    __builtin_amdgcn_sched_barrier(0);
    const bf16* Asb = smem + cur*16384;
    const bf16* Bsb = Asb + 8192;
    bf16x8 af[4][2], bfv[4][2];
    #pragma unroll
    for (int m=0;m<4;m++){
      int row = wr*64 + m*16 + lr;
      af[m][0] = ld8swz(Asb, row, lg*16);
      af[m][1] = ld8swz(Asb, row, lg*16 + 64);
    }
    #pragma unroll
    for (int n=0;n<4;n++){
      int row = wc*64 + n*16 + lr;
      bfv[n][0] = ld8swz(Bsb, row, lg*16);
      bfv[n][1] = ld8swz(Bsb, row, lg*16 + 64);
    }
    #pragma unroll
    for (int m=0;m<4;m++)
      #pragma unroll
      for (int n=0;n<4;n++){
        acc[m][n] = __builtin_amdgcn_mfma_f32_16x16x32_bf16(af[m][0], bfv[n][0], acc[m][n],0,0,0);
        acc[m][n] = __builtin_amdgcn_mfma_f32_16x16x32_bf16(af[m][1], bfv[n][1], acc[m][n],0,0,0);
      }
    __builtin_amdgcn_sched_barrier(0);
    SBAR();      // all waves done reading buf cur before next iter's loads overwrite it
    cur ^= 1;
  }

  if (MODE==0){
    if (blockIdx.z == 2){
      __syncthreads();
      #pragma unroll
      for (int n=0;n<4;n++){
        int c = wc*64 + n*16 + lr;
        float bias = bsel[n0 + c];
        #pragma unroll
        for (int m=0;m<4;m++){
          int r0 = wr*64 + m*16 + lg*4;
          s16x4 pk;
          #pragma unroll
          for (int j=0;j<4;j++) pk[j] = bf16bits(acc[m][n][j] + bias);
          *(s16x4*)((char*)smem + c*256 + ((r0*2) ^ ((c&7)<<4))) = pk;
        }
      }
      __syncthreads();
      #pragma unroll
      for (int q=0;q<8;q++){
        int idx = tid + q*256;
        int c = idx>>4, r8 = idx&15;
        bf16x8 vv = *(const bf16x8*)((char*)smem + c*256 + ((r8*16) ^ ((c&7)<<4)));
        int col = n0 + c;  int h = col>>6, dd = col&63;
        int row0 = m0 + r8*8;  int bb = row0>>10, s0 = row0&1023;
        *(bf16x8*)(o2 + ((((size_t)bb*H_ + h)*DK_ + dd)<<10) + s0) = vv;
      }
    } else {
      bf16* osel = (blockIdx.z==0) ? o0 : o1;
      const float qs = (blockIdx.z==0) ? QSCALE : 1.0f;   // pre-scale Q for exp2-domain scores
      #pragma unroll
      for (int n=0;n<4;n++){
        int col = n0 + wc*64 + n*16 + lr;
        float bias = bsel[col];
        int h = col>>6, dd = col&63;
        #pragma unroll
        for (int m=0;m<4;m++)
          #pragma unroll
          for (int j=0;j<4;j++){
            int row = m0 + wr*64 + m*16 + lg*4 + j;
            int bb = row>>10, s = row&1023;
            osel[((((size_t)bb*H_ + h)<<10) + s)*DK_ + dd] = __float2bfloat16((acc[m][n][j] + bias)*qs);
          }
      }
    }
  } else {
    #pragma unroll
    for (int n=0;n<4;n++){
      int col = n0 + wc*64 + n*16 + lr;
      float bias = bsel[col];
      #pragma unroll
      for (int m=0;m<4;m++)
        #pragma unroll
        for (int j=0;j<4;j++){
          int row = m0 + wr*64 + m*16 + lg*4 + j;
          size_t idx = (((size_t)row)<<10) + col;
          xout[idx] = acc[m][n][j] + bias + resid[idx];
        }
    }
  }
}

// ---------------- fused causal attention: r12 structure, SINGLE barrier per tile + setprio ----
// r12-benched base (72 us). One change: loop reordered to {VMCNT(0); SBAR; STAGE(t+1); compute(t)}
// — safe because a wave reaches SBAR(t) only after its compute(t-1) consumed its ds_reads, so
// STAGE(t+1)'s writes to buf cur^1 (read during t-1) cannot race. Halves barrier events.
// T5: setprio(1) around MFMA clusters (2 independent blocks/CU -> scheduler has waves to favor).
__global__ __launch_bounds__(512) void attn_kernel(
    const bf16* __restrict__ Q, const bf16* __restrict__ K, const bf16* __restrict__ Vt_g,
    const int* __restrict__ seqm, const float* __restrict__ vmean, bf16* __restrict__ ctxout)
{
  __shared__ bf16 Ks[2][64*64];   // K tile   [kv][d], swizzled, double-buffered
  __shared__ bf16 Vs[2][64*64];   // V^T tile [d][kv], swizzled, double-buffered
  __shared__ bf16 Ps[8][32*72];   // per-wave P scratch, padded
  __shared__ int msk[1024];
  const int tid = threadIdx.x, wid = tid>>6, lane = tid&63;
  const int lr = lane&15, lg = lane>>4;
  const int bh = blockIdx.x, xb = blockIdx.y;
  const int b = bh>>4, h = bh&15;
  const bf16* Qb  = Q    + (size_t)bh * S_ * DK_;
  const bf16* Kb  = K    + (size_t)bh * S_ * DK_;
  const bf16* Vtb = Vt_g + (size_t)bh * DK_ * S_;
  for (int i=tid;i<1024;i+=512) msk[i] = seqm[b*1024+i];

  const int g0 = 8*xb + wid;
  const int rb0 = g0*16;             // low group
  const int rb1 = (63 - g0)*16;      // high group (rb1 > rb0 always)
  bf16x8 qf[2][2];
  {
    const bf16* p0 = Qb + (size_t)(rb0+lr)*DK_ + lg*8;
    const bf16* p1 = Qb + (size_t)(rb1+lr)*DK_ + lg*8;
    qf[0][0] = ld8(p0); qf[0][1] = ld8(p0+32);
    qf[1][0] = ld8(p1); qf[1][1] = ld8(p1+32);
  }
  f32x4 cacc[2][4] = {};
  float lsum[2][4] = {};

  auto STAGE = [&](int t, int bsel){
    const int j0 = t*64;
    int off = (wid<<10) + (lane<<4);
    int row = off>>7;
    int colb = (off&127) ^ ((row&7)<<4);
    GLOAD_LDS16(Kb  + (size_t)(j0+row)*DK_ + (colb>>1), (char*)&Ks[bsel][0] + (wid<<10));
    GLOAD_LDS16(Vtb + (((size_t)row)<<10) + j0 + (colb>>1), (char*)&Vs[bsel][0] + (wid<<10));
  };

  STAGE(0, 0);
  __syncthreads();   // tile0 + msk ready

  // per-lane key-padding bitmask: bit i = msk[i*16 + lr]
  ull mbits = 0;
  #pragma unroll
  for (int i=0;i<64;i++) mbits |= ((ull)(msk[i*16+lr]!=0)) << i;

  const int bnt = ((1023 - 128*xb) >> 6) + 1;    // 16,14,12,10 for xb=0..3

  int cur = 0;
  for (int t=0; t<bnt; t++){
    VMCNT(0);    // this wave's STAGE(t) loads (issued last iter) have landed
    SBAR();      // everyone's stage(t) landed AND everyone finished reading buf cur^1
    if (t+1 < bnt) STAGE(t+1, cur^1);   // prefetch flies under compute(t)
    const int j0 = t*64;
    if (j0 <= rb1 + 15){
      const bool act0 = (j0 <= rb0 + 15);
      bf16x8 kf[4][2];
      #pragma unroll
      for (int nf=0;nf<4;nf++){
        kf[nf][0] = ld8swz(&Ks[cur][0], nf*16+lr, lg*16);
        kf[nf][1] = ld8swz(&Ks[cur][0], nf*16+lr, lg*16 + 64);
      }
      // per-nf key-padding addend (shared by both frags)
      float madd[4];
      #pragma unroll
      for (int nf=0;nf<4;nf++)
        madd[nf] = ((mbits >> (t*4 + nf)) & 1ull) ? 0.f : -1.0e9f;

      #pragma unroll
      for (int mf=0;mf<2;mf++){
        if (mf==0 && !act0) continue;
        const int rbm = mf ? rb1 : rb0;
        const bool diag = (j0 + 63 > rbm);   // tile touches/crosses the diagonal
        f32x4 sc[4] = {};
        __builtin_amdgcn_s_setprio(1);
        #pragma unroll
        for (int nf=0;nf<4;nf++){
          sc[nf] = __builtin_amdgcn_mfma_f32_16x16x32_bf16(qf[mf][0], kf[nf][0], sc[nf],0,0,0);
          sc[nf] = __builtin_amdgcn_mfma_f32_16x16x32_bf16(qf[mf][1], kf[nf][1], sc[nf],0,0,0);
        }
        __builtin_amdgcn_s_setprio(0);
        // static-max softmax: p = exp2(s + madd); per-lane partial row-sum only
        #pragma unroll
        for (int j=0;j<4;j++){
          int row = rbm + lg*4 + j;
          float ps = 0.f;
          #pragma unroll
          for (int nf=0;nf<4;nf++){
            float s = sc[nf][j] + madd[nf];
            if (diag){
              int col = j0 + nf*16 + lr;
              s = (col <= row) ? s : -1.0e9f;
            }
            float p = exp2f(s);
            sc[nf][j] = p;
            ps += p;
          }
          lsum[mf][j] += ps;
        }
        #pragma unroll
        for (int nf=0;nf<4;nf++)
          #pragma unroll
          for (int j=0;j<4;j++)
            Ps[wid][(mf*16+lg*4+j)*72 + nf*16+lr] = __float2bfloat16(sc[nf][j]);
      }
      // PV
      bf16x8 pf[2][2];
      #pragma unroll
      for (int mf=0;mf<2;mf++){
        if (mf==0 && !act0) continue;
        const bf16* p = &Ps[wid][(mf*16+lr)*72 + lg*8];
        pf[mf][0] = *(const bf16x8*)p; pf[mf][1] = *(const bf16x8*)(p+32);
      }
      __builtin_amdgcn_s_setprio(1);
      #pragma unroll
      for (int df=0;df<4;df++){
        #pragma unroll
        for (int kk=0;kk<2;kk++){
          bf16x8 vf = ld8swz(&Vs[cur][0], df*16+lr, lg*16 + kk*64);
          if (act0)
            cacc[0][df] = __builtin_amdgcn_mfma_f32_16x16x32_bf16(pf[0][kk], vf, cacc[0][df],0,0,0);
          cacc[1][df] = __builtin_amdgcn_mfma_f32_16x16x32_bf16(pf[1][kk], vf, cacc[1][df],0,0,0);
        }
      }
      __builtin_amdgcn_s_setprio(0);
    }
    cur ^= 1;
  }

  #pragma unroll
  for (int mf=0;mf<2;mf++){
    const int rbm = mf ? rb1 : rb0;
    float lt[4];
    #pragma unroll
    for (int j=0;j<4;j++) lt[j] = red16add(lsum[mf][j]);   // row-sum reduce, once
    #pragma unroll
    for (int df=0;df<4;df++)
      #pragma unroll
      for (int j=0;j<4;j++){
        int srow = rbm + lg*4 + j;
        int dd = df*16 + lr;
        float v = cacc[mf][df][j] / lt[j];
        if (lt[j] <= 1.0e-30f) v = vmean[bh*64 + dd];  // fully-masked row (lsum == 0)
        ctxout[((size_t)b*S_ + srow)*D_ + h*DK_ + dd] = __float2bfloat16(v);
      }
  }
}

// ---------------- LayerNorm ----------------
__global__ __launch_bounds__(256) void ln_kernel(const float* __restrict__ X2,
    const float* __restrict__ gamma, const float* __restrict__ beta, float* __restrict__ out)
{
  const int row = blockIdx.x, tid = threadIdx.x;
  const int lane = tid&63, wid = tid>>6;
  const f32x4* xr = (const f32x4*)(X2 + (((size_t)row)<<10));
  f32x4 v = xr[tid];
  float s  = v[0]+v[1]+v[2]+v[3];
  float s2 = v[0]*v[0]+v[1]*v[1]+v[2]*v[2]+v[3]*v[3];
  #pragma unroll
  for (int off=1;off<64;off<<=1){ s += __shfl_xor(s,off); s2 += __shfl_xor(s2,off); }
  __shared__ float red[8];
  if (lane==0){ red[wid]=s; red[wid+4]=s2; }
  __syncthreads();
  s  = red[0]+red[1]+red[2]+red[3];
  s2 = red[4]+red[5]+red[6]+red[7];
  float mu  = s*(1.f/1024.f);
  float var = s2*(1.f/1024.f) - mu*mu;
  float inv = rsqrtf(var + 1e-5f);
  f32x4 gv = ((const f32x4*)gamma)[tid], bv = ((const f32x4*)beta)[tid];
  f32x4 o;
  #pragma unroll
  for (int c=0;c<4;c++) o[c] = (v[c]-mu)*inv*gv[c] + bv[c];
  ((f32x4*)(out + (((size_t)row)<<10)))[tid] = o;
}

extern "C" void kernel_launch(void* const* d_in, const int* in_sizes, int n_in,
                              void* d_out, int out_size, void* d_ws, size_t ws_size,
                              hipStream_t stream) {
  const float* X   = (const float*)d_in[0];
  const int*   sm  = (const int*)d_in[1];
  const float* Wq  = (const float*)d_in[2];  const float* bq = (const float*)d_in[3];
  const float* Wk  = (const float*)d_in[4];  const float* bk = (const float*)d_in[5];
  const float* Wv  = (const float*)d_in[6];  const float* bv = (const float*)d_in[7];
  const float* Wo  = (const float*)d_in[8];  const float* bo = (const float*)d_in[9];
  const float* ga  = (const float*)d_in[10]; const float* be = (const float*)d_in[11];
  float* out = (float*)d_out;
  char* ws = (char*)d_ws;

  bf16* Xbf = (bf16*)(ws);                       // 16 MB
  bf16* Wqb = (bf16*)(ws + (16u<<20));           // 2 MB each, contiguous
  bf16* Wkb = (bf16*)(ws + (18u<<20));
  bf16* Wvb = (bf16*)(ws + (20u<<20));
  bf16* Wob = (bf16*)(ws + (22u<<20));
  bf16* Qh  = (bf16*)(ws + (24u<<20));           // 16 MB  [B,H,S,dk] (pre-scaled)
  bf16* Kh  = (bf16*)(ws + (40u<<20));           // 16 MB  [B,H,S,dk]
  bf16* Vth = (bf16*)(ws + (56u<<20));           // 16 MB  V^T [B,H,dk,S]
  bf16* Ctx = (bf16*)(ws + (72u<<20));           // 16 MB  [B,S,D]
  float* X2 = (float*)(ws + (24u<<20));          // 32 MB, aliases Qh/Kh (dead after attn)
  float* vmean = (float*)(ws + (16u<<20));       // 32 KB, aliases Wqb (dead after gemm<0>)

  cast_f32_bf16<<<4096,256,0,stream>>>(X,  Xbf, M_*D_);
  cast_w4<<<2048,256,0,stream>>>(Wq, Wk, Wv, Wo, Wqb);

  dim3 g1(M_/128, D_/128, 3);
  gemm128<0><<<g1,256,0,stream>>>(Xbf, Wqb,Wkb,Wvb, bq,bk,bv, Qh,Kh,Vth, nullptr, nullptr);

  vmean_kernel<<<B_*H_*DK_/4,256,0,stream>>>(Vth, vmean);

  dim3 g2(B_*H_, 4);
  attn_kernel<<<g2,512,0,stream>>>(Qh, Kh, Vth, sm, vmean, Ctx);

  dim3 g3(M_/128, D_/128, 1);
  gemm128<1><<<g3,256,0,stream>>>(Ctx, Wob,nullptr,nullptr, bo,nullptr,nullptr,
                                  nullptr,nullptr,nullptr, X, X2);

  ln_kernel<<<M_,256,0,stream>>>(X2, ga, be, out);
}